// Round 1
// baseline (4411.382 us; speedup 1.0000x reference)
//
#include <hip/hip_runtime.h>
#include <hip/hip_bf16.h>

// ---------------------------------------------------------------------------
// RecurrentAutoencoder on MI355X.
// Stage A: LSTM e1  (B=4096, T=140, in=1,  hid=128)  -> h1[4096][128]
// Stage B: U = Wih_e2 @ h1 + biases (parallel), then serial scan T=4096 -> z[64]
// Stage C+D: decoder LSTMs fused, T=140, single workgroup -> out[140]
// ---------------------------------------------------------------------------

__device__ __forceinline__ float sigm(float x) {
  return 1.0f / (1.0f + __expf(-x));
}
__device__ __forceinline__ float tanh_fast(float x) {
  // 1 - 2/(e^{2x}+1); saturates correctly for |x| large.
  return 1.0f - 2.0f / (__expf(2.0f * x) + 1.0f);
}

// ---------------------------------------------------------------------------
// Stage A: one workgroup handles A_BB batches; thread j owns gate row j.
// Gate order (PyTorch): rows [0:128)=i, [128:256)=f, [256:384)=g, [384:512)=o
// ---------------------------------------------------------------------------
#define A_BB 16

__global__ __launch_bounds__(512, 1) void lstm_e1_kernel(
    const float* __restrict__ x,     // [4096][140]  (x[b][t])
    const float* __restrict__ Wih,   // [512][1]
    const float* __restrict__ Whh,   // [512][128]
    const float* __restrict__ bih,   // [512]
    const float* __restrict__ bhh,   // [512]
    float* __restrict__ h1_out)      // [4096][128]
{
  const int j  = threadIdx.x;        // 0..511 : gate row
  const int b0 = blockIdx.x * A_BB;

  __shared__ float Hs[A_BB][128];
  __shared__ float Cs[A_BB][128];
  __shared__ float Gs[A_BB][512];
  __shared__ float xs[A_BB];

  for (int i = j; i < A_BB * 128; i += 512) {
    ((float*)Hs)[i] = 0.0f;
    ((float*)Cs)[i] = 0.0f;
  }
  if (j < A_BB) xs[j] = x[(b0 + j) * 140 + 0];

  // Whh row resident in VGPRs (fully static indexing).
  float wrow[128];
#pragma unroll
  for (int k = 0; k < 128; k += 4)
    *(float4*)&wrow[k] = *(const float4*)&Whh[j * 128 + k];

  const float wih  = Wih[j];
  const float bias = bih[j] + bhh[j];
  const bool  is_g = (j >= 256) && (j < 384);

  __syncthreads();

  for (int t = 0; t < 140; ++t) {
    // ---- matvec phase: gates for all A_BB batches --------------------------
    for (int b = 0; b < A_BB; ++b) {
      float a0 = 0.f, a1 = 0.f, a2 = 0.f, a3 = 0.f;
#pragma unroll
      for (int k = 0; k < 128; k += 4) {
        const float4 hv = *(const float4*)&Hs[b][k];  // wave-uniform: broadcast
        a0 = __builtin_fmaf(wrow[k + 0], hv.x, a0);
        a1 = __builtin_fmaf(wrow[k + 1], hv.y, a1);
        a2 = __builtin_fmaf(wrow[k + 2], hv.z, a2);
        a3 = __builtin_fmaf(wrow[k + 3], hv.w, a3);
      }
      const float pre = __builtin_fmaf(xs[b], wih, bias) + ((a0 + a1) + (a2 + a3));
      Gs[b][j] = is_g ? tanh_fast(pre) : sigm(pre);
    }
    __syncthreads();

    // ---- update phase: each thread updates 4 hidden units of one batch -----
    {
      const int b = j >> 5;
      const int m = (j & 31) << 2;
      const float4 iv = *(const float4*)&Gs[b][m];
      const float4 fv = *(const float4*)&Gs[b][128 + m];
      const float4 gv = *(const float4*)&Gs[b][256 + m];
      const float4 ov = *(const float4*)&Gs[b][384 + m];
      const float4 cv = *(const float4*)&Cs[b][m];
      float4 nc, nh;
      nc.x = fv.x * cv.x + iv.x * gv.x;  nh.x = ov.x * tanh_fast(nc.x);
      nc.y = fv.y * cv.y + iv.y * gv.y;  nh.y = ov.y * tanh_fast(nc.y);
      nc.z = fv.z * cv.z + iv.z * gv.z;  nh.z = ov.z * tanh_fast(nc.z);
      nc.w = fv.w * cv.w + iv.w * gv.w;  nh.w = ov.w * tanh_fast(nc.w);
      *(float4*)&Cs[b][m] = nc;
      *(float4*)&Hs[b][m] = nh;
      if (j < A_BB && (t + 1) < 140) xs[j] = x[(b0 + j) * 140 + (t + 1)];
    }
    __syncthreads();
  }

  // final h -> h1_out
  {
    const int b = j >> 5;
    const int m = (j & 31) << 2;
    *(float4*)&h1_out[(b0 + b) * 128 + m] = *(const float4*)&Hs[b][m];
  }
}

// ---------------------------------------------------------------------------
// Stage B input projection: U[t][j] = Wih_e2[j,:] . h1[t,:] + bih[j] + bhh[j]
// ---------------------------------------------------------------------------
__global__ __launch_bounds__(256, 1) void u_pre_kernel(
    const float* __restrict__ h1,   // [4096][128]
    const float* __restrict__ Wih,  // [256][128]
    const float* __restrict__ bih,  // [256]
    const float* __restrict__ bhh,  // [256]
    float* __restrict__ U)          // [4096][256]
{
  const int t = blockIdx.x;
  const int j = threadIdx.x;
  __shared__ float hs[128];
  if (j < 128) hs[j] = h1[t * 128 + j];
  __syncthreads();
  float acc = bih[j] + bhh[j];
#pragma unroll
  for (int k = 0; k < 128; k += 4) {
    const float4 hv = *(const float4*)&hs[k];
    const float4 wv = *(const float4*)&Wih[j * 128 + k];
    acc += wv.x * hv.x + wv.y * hv.y + wv.z * hv.z + wv.w * hv.w;
  }
  U[t * 256 + j] = acc;
}

// ---------------------------------------------------------------------------
// Stage B serial scan: T=4096 steps, hid=64. Single block of 256 threads,
// thread j owns gate row j. c-state lives in registers of threads j<64.
// Gate order: [0:64)=i, [64:128)=f, [128:192)=g, [192:256)=o
// ---------------------------------------------------------------------------
__global__ __launch_bounds__(256, 1) void lstm_e2_scan_kernel(
    const float* __restrict__ U,    // [4096][256]  (biases already folded in)
    const float* __restrict__ Whh,  // [256][64]
    float* __restrict__ z_out)      // [64]
{
  const int j = threadIdx.x;
  __shared__ float h_lds[64];
  __shared__ float act[256];

  float wrow[64];
#pragma unroll
  for (int k = 0; k < 64; k += 4)
    *(float4*)&wrow[k] = *(const float4*)&Whh[j * 64 + k];

  float cm = 0.0f;
  if (j < 64) h_lds[j] = 0.0f;
  const bool is_g = (j >= 128) && (j < 192);

  float Ubuf = U[j];  // prefetch t=0
  __syncthreads();

  for (int t = 0; t < 4096; ++t) {
    const int tn = (t + 1 < 4096) ? (t + 1) : 4095;
    const float Unext = U[tn * 256 + j];  // prefetch next step's U

    float a0 = 0.f, a1 = 0.f, a2 = 0.f, a3 = 0.f;
#pragma unroll
    for (int k = 0; k < 64; k += 4) {
      const float4 hv = *(const float4*)&h_lds[k];
      a0 = __builtin_fmaf(wrow[k + 0], hv.x, a0);
      a1 = __builtin_fmaf(wrow[k + 1], hv.y, a1);
      a2 = __builtin_fmaf(wrow[k + 2], hv.z, a2);
      a3 = __builtin_fmaf(wrow[k + 3], hv.w, a3);
    }
    const float pre = Ubuf + ((a0 + a1) + (a2 + a3));
    act[j] = is_g ? tanh_fast(pre) : sigm(pre);
    __syncthreads();

    if (j < 64) {
      const float gi = act[j];
      const float gf = act[64 + j];
      const float gg = act[128 + j];
      const float go = act[192 + j];
      cm = gf * cm + gi * gg;
      h_lds[j] = go * tanh_fast(cm);
    }
    Ubuf = Unext;
    __syncthreads();
  }

  if (j < 64) z_out[j] = h_lds[j];
}

// ---------------------------------------------------------------------------
// Stage C+D fused decoder: d1 (in=64 const z, hid=128) feeding d2 (in=128,
// hid=1), T=140. Single block of 512 threads; wave 0 does d2 via shuffles.
// ---------------------------------------------------------------------------
__global__ __launch_bounds__(512, 1) void lstm_dec_kernel(
    const float* __restrict__ z,      // [64]
    const float* __restrict__ Wih1,   // [512][64]
    const float* __restrict__ Whh1,   // [512][128]
    const float* __restrict__ bih1,   // [512]
    const float* __restrict__ bhh1,   // [512]
    const float* __restrict__ Wih2,   // [4][128]
    const float* __restrict__ Whh2,   // [4][1]
    const float* __restrict__ bih2,   // [4]
    const float* __restrict__ bhh2,   // [4]
    float* __restrict__ out)          // [140]
{
  const int j = threadIdx.x;
  __shared__ float h_lds[128];
  __shared__ float act[512];
  __shared__ float zs[64];

  if (j < 64) zs[j] = z[j];
  if (j < 128) h_lds[j] = 0.0f;
  __syncthreads();

  float wrow[128];
#pragma unroll
  for (int k = 0; k < 128; k += 4)
    *(float4*)&wrow[k] = *(const float4*)&Whh1[j * 128 + k];

  // constant input projection: Wih1[j,:64] . z + biases
  float pre0 = bih1[j] + bhh1[j];
#pragma unroll
  for (int k = 0; k < 64; k += 4) {
    const float4 zv = *(const float4*)&zs[k];
    const float4 wv = *(const float4*)&Wih1[j * 64 + k];
    pre0 += wv.x * zv.x + wv.y * zv.y + wv.z * zv.z + wv.w * zv.w;
  }
  const bool is_g = (j >= 256) && (j < 384);

  float cm = 0.0f;  // d1 cell state for threads j<128

  // d2 per-lane data (wave 0 only, but load unconditionally-guarded)
  float w2[8];   // w2[g*2+e] = Wih2[g][2*lane+e]
  float b2[4], wh2[4];
  if (j < 64) {
#pragma unroll
    for (int g = 0; g < 4; ++g) {
      w2[g * 2 + 0] = Wih2[g * 128 + 2 * j + 0];
      w2[g * 2 + 1] = Wih2[g * 128 + 2 * j + 1];
      b2[g]  = bih2[g] + bhh2[g];
      wh2[g] = Whh2[g];
    }
  }
  float c2 = 0.0f, h2 = 0.0f;  // consistent across all lanes of wave 0

  for (int t = 0; t < 140; ++t) {
    // ---- d1 matvec ---------------------------------------------------------
    float a0 = 0.f, a1 = 0.f, a2 = 0.f, a3 = 0.f;
#pragma unroll
    for (int k = 0; k < 128; k += 4) {
      const float4 hv = *(const float4*)&h_lds[k];
      a0 = __builtin_fmaf(wrow[k + 0], hv.x, a0);
      a1 = __builtin_fmaf(wrow[k + 1], hv.y, a1);
      a2 = __builtin_fmaf(wrow[k + 2], hv.z, a2);
      a3 = __builtin_fmaf(wrow[k + 3], hv.w, a3);
    }
    const float pre = pre0 + ((a0 + a1) + (a2 + a3));
    act[j] = is_g ? tanh_fast(pre) : sigm(pre);
    __syncthreads();

    // ---- d1 state update ---------------------------------------------------
    if (j < 128) {
      const float gi = act[j];
      const float gf = act[128 + j];
      const float gg = act[256 + j];
      const float go = act[384 + j];
      cm = gf * cm + gi * gg;
      h_lds[j] = go * tanh_fast(cm);
    }
    __syncthreads();

    // ---- d2 step on wave 0 -------------------------------------------------
    if (j < 64) {
      const float hA = h_lds[2 * j + 0];
      const float hB = h_lds[2 * j + 1];
      float p0 = hA * w2[0] + hB * w2[1];
      float p1 = hA * w2[2] + hB * w2[3];
      float p2 = hA * w2[4] + hB * w2[5];
      float p3 = hA * w2[6] + hB * w2[7];
#pragma unroll
      for (int s = 1; s < 64; s <<= 1) {
        p0 += __shfl_xor(p0, s);
        p1 += __shfl_xor(p1, s);
        p2 += __shfl_xor(p2, s);
        p3 += __shfl_xor(p3, s);
      }
      const float gi = sigm(p0 + b2[0] + wh2[0] * h2);
      const float gf = sigm(p1 + b2[1] + wh2[1] * h2);
      const float gg = tanh_fast(p2 + b2[2] + wh2[2] * h2);
      const float go = sigm(p3 + b2[3] + wh2[3] * h2);
      c2 = gf * c2 + gi * gg;
      h2 = go * tanh_fast(c2);
      if (j == 0) out[t] = h2;
    }
  }
}

// ---------------------------------------------------------------------------
extern "C" void kernel_launch(void* const* d_in, const int* in_sizes, int n_in,
                              void* d_out, int out_size, void* d_ws, size_t ws_size,
                              hipStream_t stream) {
  const float* x      = (const float*)d_in[0];
  const float* Wih_e1 = (const float*)d_in[1];
  const float* Whh_e1 = (const float*)d_in[2];
  const float* bih_e1 = (const float*)d_in[3];
  const float* bhh_e1 = (const float*)d_in[4];
  const float* Wih_e2 = (const float*)d_in[5];
  const float* Whh_e2 = (const float*)d_in[6];
  const float* bih_e2 = (const float*)d_in[7];
  const float* bhh_e2 = (const float*)d_in[8];
  const float* Wih_d1 = (const float*)d_in[9];
  const float* Whh_d1 = (const float*)d_in[10];
  const float* bih_d1 = (const float*)d_in[11];
  const float* bhh_d1 = (const float*)d_in[12];
  const float* Wih_d2 = (const float*)d_in[13];
  const float* Whh_d2 = (const float*)d_in[14];
  const float* bih_d2 = (const float*)d_in[15];
  const float* bhh_d2 = (const float*)d_in[16];

  float* out = (float*)d_out;  // 140 floats

  // workspace layout
  float* h1 = (float*)d_ws;              // 4096*128
  float* U  = h1 + 4096 * 128;           // 4096*256
  float* zb = U + 4096 * 256;            // 64

  lstm_e1_kernel<<<4096 / A_BB, 512, 0, stream>>>(x, Wih_e1, Whh_e1, bih_e1, bhh_e1, h1);
  u_pre_kernel<<<4096, 256, 0, stream>>>(h1, Wih_e2, bih_e2, bhh_e2, U);
  lstm_e2_scan_kernel<<<1, 256, 0, stream>>>(U, Whh_e2, zb);
  lstm_dec_kernel<<<1, 512, 0, stream>>>(zb, Wih_d1, Whh_d1, bih_d1, bhh_d1,
                                         Wih_d2, Whh_d2, bih_d2, bhh_d2, out);
}

// Round 2
// 3907.095 us; speedup vs baseline: 1.1291x; 1.1291x over previous
//
#include <hip/hip_runtime.h>
#include <hip/hip_bf16.h>

// ---------------------------------------------------------------------------
// RecurrentAutoencoder on MI355X (gfx950).
// Stage A: LSTM e1  (B=4096, T=140, in=1,  hid=128)  -> h1[4096][128]
// Stage B: Up = permuted input-projection (parallel), serial scan T=4096 -> z
// Stage C+D: decoder LSTMs fused, T=140, single workgroup -> out[140]
//
// Core idiom everywhere: thread (unit u, k-quarter q) computes ALL FOUR gate
// rows of hidden unit u over its k-quarter; quad lanes (same u, q=0..3) reduce
// via ds_swizzle quad-perm. No LDS round-trip for gates, ONE barrier per step.
// ---------------------------------------------------------------------------

__device__ __forceinline__ float sigm(float x) {
  return 1.0f / (1.0f + __expf(-x));
}
__device__ __forceinline__ float tanh_fast(float x) {
  return 1.0f - 2.0f / (__expf(2.0f * x) + 1.0f);
}

// quad-perm lane shuffle (groups of 4): IMM = 0x8000 | sel0|sel1<<2|sel2<<4|sel3<<6
template <int IMM>
__device__ __forceinline__ float qp(float v) {
  return __int_as_float(__builtin_amdgcn_ds_swizzle(__float_as_int(v), IMM));
}
#define QP_XOR1 0x80B1  // dest q <- q^1
#define QP_XOR2 0x804E  // dest q <- q^2
#define QP_ROT1 0x8093  // dest q <- (q-1)&3   (ring rotate +1)

// swizzled LDS column for 128-wide rows: quarter q shifted by 4 floats
__device__ __forceinline__ int swzc(int k) { return k + ((k >> 5) << 2); }

#define A_BB 16

// ---------------------------------------------------------------------------
// Stage A. 512 threads = 8 waves. Thread: u = wave*16 + (lane>>2) in [0,128),
// q = lane&3. Owns gate rows {u,128+u,256+u,384+u}, k in [32q,32q+32), and the
// c-state of unit u for batches [4q,4q+4). 4-stage ring reduce-scatter puts the
// complete gate sums for exactly those batches in static registers R[g][i].
// ---------------------------------------------------------------------------
__global__ __launch_bounds__(512, 2) void lstm_e1_kernel(
    const float* __restrict__ x,     // [4096][140]
    const float* __restrict__ Wih,   // [512][1]
    const float* __restrict__ Whh,   // [512][128]
    const float* __restrict__ bih,   // [512]
    const float* __restrict__ bhh,   // [512]
    float* __restrict__ h1_out)      // [4096][128]
{
  const int j    = threadIdx.x;
  const int lane = j & 63;
  const int w    = j >> 6;
  const int u    = w * 16 + (lane >> 2);  // 0..127
  const int q    = lane & 3;
  const int b0   = blockIdx.x * A_BB;

  __shared__ float Hs[2][A_BB][144];  // swizzled columns (swzc(k) <= 139)
  __shared__ float xs[2][A_BB];

  for (int i = j; i < A_BB * 144; i += 512) ((float*)Hs[0])[i] = 0.0f;
  if (j < A_BB) xs[0][j] = x[(b0 + j) * 140];

  // weights: 4 gate rows x 32 k  = 128 VGPRs
  float wr[4][32];
#pragma unroll
  for (int g = 0; g < 4; ++g)
#pragma unroll
    for (int k = 0; k < 32; k += 4)
      *(float4*)&wr[g][k] = *(const float4*)&Whh[(g * 128 + u) * 128 + q * 32 + k];

  float wih[4], bs[4];
#pragma unroll
  for (int g = 0; g < 4; ++g) {
    wih[g] = Wih[g * 128 + u];
    bs[g]  = bih[g * 128 + u] + bhh[g * 128 + u];
  }

  float c[4]  = {0.f, 0.f, 0.f, 0.f};
  float hr[4] = {0.f, 0.f, 0.f, 0.f};
  __syncthreads();

  int cur = 0;
  for (int t = 0; t < 140; ++t) {
    const int nxt = cur ^ 1;

    // ring accumulator: R[g][i] ends as full gate-g sum for batch 4q+i
    float R[4][4];
#pragma unroll
    for (int g = 0; g < 4; ++g)
#pragma unroll
      for (int i = 0; i < 4; ++i) R[g][i] = 0.0f;

#pragma unroll
    for (int s = 0; s < 4; ++s) {
      if (s) {
#pragma unroll
        for (int g = 0; g < 4; ++g)
#pragma unroll
          for (int i = 0; i < 4; ++i) R[g][i] = qp<QP_ROT1>(R[g][i]);
      }
      const int cch = (q - 1 - s) & 3;  // batch chunk visited this stage
      const float* hbase = &Hs[cur][cch * 4][q * 36];
#pragma unroll
      for (int i = 0; i < 4; ++i) {
        const float* hrow = hbase + i * 144;
#pragma unroll
        for (int kk = 0; kk < 8; ++kk) {
          const float4 hv = *(const float4*)&hrow[kk * 4];
#pragma unroll
          for (int g = 0; g < 4; ++g) {
            R[g][i] = __builtin_fmaf(wr[g][kk * 4 + 0], hv.x, R[g][i]);
            R[g][i] = __builtin_fmaf(wr[g][kk * 4 + 1], hv.y, R[g][i]);
            R[g][i] = __builtin_fmaf(wr[g][kk * 4 + 2], hv.z, R[g][i]);
            R[g][i] = __builtin_fmaf(wr[g][kk * 4 + 3], hv.w, R[g][i]);
          }
        }
      }
    }

    // prefetch next x slice
    if (j < A_BB && (t + 1) < 140) xs[nxt][j] = x[(b0 + j) * 140 + t + 1];

    // update batches 4q..4q+3 (c-state in registers, static indices)
    const float4 xv = *(const float4*)&xs[cur][q * 4];
    const float xa[4] = {xv.x, xv.y, xv.z, xv.w};
#pragma unroll
    for (int i = 0; i < 4; ++i) {
      const float gi = sigm(R[0][i] + __builtin_fmaf(wih[0], xa[i], bs[0]));
      const float gf = sigm(R[1][i] + __builtin_fmaf(wih[1], xa[i], bs[1]));
      const float gg = tanh_fast(R[2][i] + __builtin_fmaf(wih[2], xa[i], bs[2]));
      const float go = sigm(R[3][i] + __builtin_fmaf(wih[3], xa[i], bs[3]));
      c[i]  = gf * c[i] + gi * gg;
      hr[i] = go * tanh_fast(c[i]);
      Hs[nxt][q * 4 + i][swzc(u)] = hr[i];
    }
    __syncthreads();
    cur = nxt;
  }

#pragma unroll
  for (int i = 0; i < 4; ++i)
    h1_out[(b0 + q * 4 + i) * 128 + u] = hr[i];
}

// ---------------------------------------------------------------------------
// Stage B input projection, PERMUTED output:
// Up[t][u] = float4( pre_i, pre_f, pre_g, pre_o ) for unit u (biases folded).
// ---------------------------------------------------------------------------
__global__ __launch_bounds__(256, 1) void u_pre_kernel(
    const float* __restrict__ h1,   // [4096][128]
    const float* __restrict__ Wih,  // [256][128]
    const float* __restrict__ bih,  // [256]
    const float* __restrict__ bhh,  // [256]
    float* __restrict__ Up)         // [4096][64][4]
{
  const int t = blockIdx.x;
  const int j = threadIdx.x;      // gate row j = g*64 + u
  __shared__ float hs[128];
  if (j < 128) hs[j] = h1[t * 128 + j];
  __syncthreads();
  float acc = bih[j] + bhh[j];
#pragma unroll
  for (int k = 0; k < 128; k += 4) {
    const float4 hv = *(const float4*)&hs[k];
    const float4 wv = *(const float4*)&Wih[j * 128 + k];
    acc += wv.x * hv.x + wv.y * hv.y + wv.z * hv.z + wv.w * hv.w;
  }
  Up[t * 256 + (j & 63) * 4 + (j >> 6)] = acc;
}

// ---------------------------------------------------------------------------
// Stage B serial scan. 256 threads = 4 waves. Thread (u = j>>2, q = j&3) owns
// gate rows {u,64+u,128+u,192+u}, k in [16q,16q+16). Quad xor-reduce; c,h
// replicated across the quad; ONE barrier per step; U prefetched 2 ahead.
// ---------------------------------------------------------------------------
__global__ __launch_bounds__(256, 1) void lstm_e2_scan_kernel(
    const float4* __restrict__ Up,  // [4096][64] of (i,f,g,o)
    const float* __restrict__ Whh,  // [256][64]
    float* __restrict__ z_out)      // [64]
{
  const int j = threadIdx.x;
  const int u = j >> 2;
  const int q = j & 3;

  __shared__ float hb[2][64];

  float wr[4][16];
#pragma unroll
  for (int g = 0; g < 4; ++g)
#pragma unroll
    for (int k = 0; k < 16; k += 4)
      *(float4*)&wr[g][k] = *(const float4*)&Whh[(g * 64 + u) * 64 + q * 16 + k];

  if (j < 64) hb[0][j] = 0.0f;
  float c = 0.0f, h = 0.0f;

  float4 U0 = Up[u];        // t = 0
  float4 U1 = Up[64 + u];   // t = 1
  __syncthreads();

  int cur = 0;
#pragma unroll 1
  for (int t = 0; t < 4096; t += 2) {
    // ---------------- step t (uses U0) ----------------
    {
      const int tp = (t + 2 < 4096) ? (t + 2) : 4095;
      const float4 Unew = Up[tp * 64 + u];
      float a0 = 0.f, a1 = 0.f, a2 = 0.f, a3 = 0.f;
#pragma unroll
      for (int kk = 0; kk < 4; ++kk) {
        const float4 hv = *(const float4*)&hb[cur][q * 16 + kk * 4];
        a0 = __builtin_fmaf(wr[0][kk*4+0], hv.x, a0); a0 = __builtin_fmaf(wr[0][kk*4+1], hv.y, a0);
        a0 = __builtin_fmaf(wr[0][kk*4+2], hv.z, a0); a0 = __builtin_fmaf(wr[0][kk*4+3], hv.w, a0);
        a1 = __builtin_fmaf(wr[1][kk*4+0], hv.x, a1); a1 = __builtin_fmaf(wr[1][kk*4+1], hv.y, a1);
        a1 = __builtin_fmaf(wr[1][kk*4+2], hv.z, a1); a1 = __builtin_fmaf(wr[1][kk*4+3], hv.w, a1);
        a2 = __builtin_fmaf(wr[2][kk*4+0], hv.x, a2); a2 = __builtin_fmaf(wr[2][kk*4+1], hv.y, a2);
        a2 = __builtin_fmaf(wr[2][kk*4+2], hv.z, a2); a2 = __builtin_fmaf(wr[2][kk*4+3], hv.w, a2);
        a3 = __builtin_fmaf(wr[3][kk*4+0], hv.x, a3); a3 = __builtin_fmaf(wr[3][kk*4+1], hv.y, a3);
        a3 = __builtin_fmaf(wr[3][kk*4+2], hv.z, a3); a3 = __builtin_fmaf(wr[3][kk*4+3], hv.w, a3);
      }
      a0 += qp<QP_XOR1>(a0); a0 += qp<QP_XOR2>(a0);
      a1 += qp<QP_XOR1>(a1); a1 += qp<QP_XOR2>(a1);
      a2 += qp<QP_XOR1>(a2); a2 += qp<QP_XOR2>(a2);
      a3 += qp<QP_XOR1>(a3); a3 += qp<QP_XOR2>(a3);
      const float gi = sigm(a0 + U0.x);
      const float gf = sigm(a1 + U0.y);
      const float gg = tanh_fast(a2 + U0.z);
      const float go = sigm(a3 + U0.w);
      c = gf * c + gi * gg;
      h = go * tanh_fast(c);
      if (q == 0) hb[cur ^ 1][u] = h;
      U0 = Unew;
      __syncthreads();
      cur ^= 1;
    }
    // ---------------- step t+1 (uses U1) ----------------
    {
      const int tp = (t + 3 < 4096) ? (t + 3) : 4095;
      const float4 Unew = Up[tp * 64 + u];
      float a0 = 0.f, a1 = 0.f, a2 = 0.f, a3 = 0.f;
#pragma unroll
      for (int kk = 0; kk < 4; ++kk) {
        const float4 hv = *(const float4*)&hb[cur][q * 16 + kk * 4];
        a0 = __builtin_fmaf(wr[0][kk*4+0], hv.x, a0); a0 = __builtin_fmaf(wr[0][kk*4+1], hv.y, a0);
        a0 = __builtin_fmaf(wr[0][kk*4+2], hv.z, a0); a0 = __builtin_fmaf(wr[0][kk*4+3], hv.w, a0);
        a1 = __builtin_fmaf(wr[1][kk*4+0], hv.x, a1); a1 = __builtin_fmaf(wr[1][kk*4+1], hv.y, a1);
        a1 = __builtin_fmaf(wr[1][kk*4+2], hv.z, a1); a1 = __builtin_fmaf(wr[1][kk*4+3], hv.w, a1);
        a2 = __builtin_fmaf(wr[2][kk*4+0], hv.x, a2); a2 = __builtin_fmaf(wr[2][kk*4+1], hv.y, a2);
        a2 = __builtin_fmaf(wr[2][kk*4+2], hv.z, a2); a2 = __builtin_fmaf(wr[2][kk*4+3], hv.w, a2);
        a3 = __builtin_fmaf(wr[3][kk*4+0], hv.x, a3); a3 = __builtin_fmaf(wr[3][kk*4+1], hv.y, a3);
        a3 = __builtin_fmaf(wr[3][kk*4+2], hv.z, a3); a3 = __builtin_fmaf(wr[3][kk*4+3], hv.w, a3);
      }
      a0 += qp<QP_XOR1>(a0); a0 += qp<QP_XOR2>(a0);
      a1 += qp<QP_XOR1>(a1); a1 += qp<QP_XOR2>(a1);
      a2 += qp<QP_XOR1>(a2); a2 += qp<QP_XOR2>(a2);
      a3 += qp<QP_XOR1>(a3); a3 += qp<QP_XOR2>(a3);
      const float gi = sigm(a0 + U1.x);
      const float gf = sigm(a1 + U1.y);
      const float gg = tanh_fast(a2 + U1.z);
      const float go = sigm(a3 + U1.w);
      c = gf * c + gi * gg;
      h = go * tanh_fast(c);
      if (q == 0) hb[cur ^ 1][u] = h;
      U1 = Unew;
      __syncthreads();
      cur ^= 1;
    }
  }
  if (q == 0) z_out[u] = h;
}

// ---------------------------------------------------------------------------
// Stage C+D fused decoder. 512 threads; thread (u = j>>2 in [0,128), q = j&3)
// runs d1 in scan style; wave 0 then runs d2 for the step via 64-lane shuffles.
// ---------------------------------------------------------------------------
__global__ __launch_bounds__(512, 1) void lstm_dec_kernel(
    const float* __restrict__ z,      // [64]
    const float* __restrict__ Wih1,   // [512][64]
    const float* __restrict__ Whh1,   // [512][128]
    const float* __restrict__ bih1,   // [512]
    const float* __restrict__ bhh1,   // [512]
    const float* __restrict__ Wih2,   // [4][128]
    const float* __restrict__ Whh2,   // [4][1]
    const float* __restrict__ bih2,   // [4]
    const float* __restrict__ bhh2,   // [4]
    float* __restrict__ out)          // [140]
{
  const int j = threadIdx.x;
  const int u = j >> 2;   // 0..127
  const int q = j & 3;

  __shared__ float hb[2][144];  // swizzled columns
  __shared__ float zs[64];

  if (j < 64) zs[j] = z[j];
  if (j < 144) hb[0][j] = 0.0f;
  __syncthreads();

  float wr[4][32];
#pragma unroll
  for (int g = 0; g < 4; ++g)
#pragma unroll
    for (int k = 0; k < 32; k += 4)
      *(float4*)&wr[g][k] = *(const float4*)&Whh1[(g * 128 + u) * 128 + q * 32 + k];

  // constant input projection per gate row
  float pre0[4];
#pragma unroll
  for (int g = 0; g < 4; ++g) {
    float acc = bih1[g * 128 + u] + bhh1[g * 128 + u];
#pragma unroll
    for (int k = 0; k < 64; k += 4) {
      const float4 zv = *(const float4*)&zs[k];
      const float4 wv = *(const float4*)&Wih1[(g * 128 + u) * 64 + k];
      acc += wv.x * zv.x + wv.y * zv.y + wv.z * zv.z + wv.w * zv.w;
    }
    pre0[g] = acc;
  }

  // d2 lane data (wave 0 lanes l: weight cols 2l, 2l+1)
  float w2[8] = {0,0,0,0,0,0,0,0}, b2[4] = {0,0,0,0}, wh2[4] = {0,0,0,0};
  if (j < 64) {
#pragma unroll
    for (int g = 0; g < 4; ++g) {
      w2[g * 2 + 0] = Wih2[g * 128 + 2 * j + 0];
      w2[g * 2 + 1] = Wih2[g * 128 + 2 * j + 1];
      b2[g]  = bih2[g] + bhh2[g];
      wh2[g] = Whh2[g];
    }
  }

  float c1 = 0.0f;
  float c2 = 0.0f, h2 = 0.0f;

  int cur = 0;
  for (int t = 0; t < 140; ++t) {
    float a0 = 0.f, a1 = 0.f, a2 = 0.f, a3 = 0.f;
#pragma unroll
    for (int kk = 0; kk < 8; ++kk) {
      const float4 hv = *(const float4*)&hb[cur][q * 36 + kk * 4];
      a0 = __builtin_fmaf(wr[0][kk*4+0], hv.x, a0); a0 = __builtin_fmaf(wr[0][kk*4+1], hv.y, a0);
      a0 = __builtin_fmaf(wr[0][kk*4+2], hv.z, a0); a0 = __builtin_fmaf(wr[0][kk*4+3], hv.w, a0);
      a1 = __builtin_fmaf(wr[1][kk*4+0], hv.x, a1); a1 = __builtin_fmaf(wr[1][kk*4+1], hv.y, a1);
      a1 = __builtin_fmaf(wr[1][kk*4+2], hv.z, a1); a1 = __builtin_fmaf(wr[1][kk*4+3], hv.w, a1);
      a2 = __builtin_fmaf(wr[2][kk*4+0], hv.x, a2); a2 = __builtin_fmaf(wr[2][kk*4+1], hv.y, a2);
      a2 = __builtin_fmaf(wr[2][kk*4+2], hv.z, a2); a2 = __builtin_fmaf(wr[2][kk*4+3], hv.w, a2);
      a3 = __builtin_fmaf(wr[3][kk*4+0], hv.x, a3); a3 = __builtin_fmaf(wr[3][kk*4+1], hv.y, a3);
      a3 = __builtin_fmaf(wr[3][kk*4+2], hv.z, a3); a3 = __builtin_fmaf(wr[3][kk*4+3], hv.w, a3);
    }
    a0 += qp<QP_XOR1>(a0); a0 += qp<QP_XOR2>(a0);
    a1 += qp<QP_XOR1>(a1); a1 += qp<QP_XOR2>(a1);
    a2 += qp<QP_XOR1>(a2); a2 += qp<QP_XOR2>(a2);
    a3 += qp<QP_XOR1>(a3); a3 += qp<QP_XOR2>(a3);

    const float gi = sigm(a0 + pre0[0]);
    const float gf = sigm(a1 + pre0[1]);
    const float gg = tanh_fast(a2 + pre0[2]);
    const float go = sigm(a3 + pre0[3]);
    c1 = gf * c1 + gi * gg;
    const float h1v = go * tanh_fast(c1);
    if (q == 0) hb[cur ^ 1][swzc(u)] = h1v;
    __syncthreads();
    cur ^= 1;

    // d2 on wave 0, reading the just-written h buffer
    if (j < 64) {
      const float hA = hb[cur][swzc(2 * j)];
      const float hB = hb[cur][swzc(2 * j + 1)];
      float p0 = hA * w2[0] + hB * w2[1];
      float p1 = hA * w2[2] + hB * w2[3];
      float p2 = hA * w2[4] + hB * w2[5];
      float p3 = hA * w2[6] + hB * w2[7];
#pragma unroll
      for (int s = 1; s < 64; s <<= 1) {
        p0 += __shfl_xor(p0, s);
        p1 += __shfl_xor(p1, s);
        p2 += __shfl_xor(p2, s);
        p3 += __shfl_xor(p3, s);
      }
      const float g2i = sigm(p0 + b2[0] + wh2[0] * h2);
      const float g2f = sigm(p1 + b2[1] + wh2[1] * h2);
      const float g2g = tanh_fast(p2 + b2[2] + wh2[2] * h2);
      const float g2o = sigm(p3 + b2[3] + wh2[3] * h2);
      c2 = g2f * c2 + g2i * g2g;
      h2 = g2o * tanh_fast(c2);
      if (j == 0) out[t] = h2;
    }
  }
}

// ---------------------------------------------------------------------------
extern "C" void kernel_launch(void* const* d_in, const int* in_sizes, int n_in,
                              void* d_out, int out_size, void* d_ws, size_t ws_size,
                              hipStream_t stream) {
  const float* x      = (const float*)d_in[0];
  const float* Wih_e1 = (const float*)d_in[1];
  const float* Whh_e1 = (const float*)d_in[2];
  const float* bih_e1 = (const float*)d_in[3];
  const float* bhh_e1 = (const float*)d_in[4];
  const float* Wih_e2 = (const float*)d_in[5];
  const float* Whh_e2 = (const float*)d_in[6];
  const float* bih_e2 = (const float*)d_in[7];
  const float* bhh_e2 = (const float*)d_in[8];
  const float* Wih_d1 = (const float*)d_in[9];
  const float* Whh_d1 = (const float*)d_in[10];
  const float* bih_d1 = (const float*)d_in[11];
  const float* bhh_d1 = (const float*)d_in[12];
  const float* Wih_d2 = (const float*)d_in[13];
  const float* Whh_d2 = (const float*)d_in[14];
  const float* bih_d2 = (const float*)d_in[15];
  const float* bhh_d2 = (const float*)d_in[16];

  float* out = (float*)d_out;  // 140 floats

  float* h1 = (float*)d_ws;              // 4096*128
  float* Up = h1 + 4096 * 128;           // 4096*256 (permuted: [t][u][gate])
  float* zb = Up + 4096 * 256;           // 64

  lstm_e1_kernel<<<4096 / A_BB, 512, 0, stream>>>(x, Wih_e1, Whh_e1, bih_e1, bhh_e1, h1);
  u_pre_kernel<<<4096, 256, 0, stream>>>(h1, Wih_e2, bih_e2, bhh_e2, Up);
  lstm_e2_scan_kernel<<<1, 256, 0, stream>>>((const float4*)Up, Whh_e2, zb);
  lstm_dec_kernel<<<1, 512, 0, stream>>>(zb, Wih_d1, Whh_d1, bih_d1, bhh_d1,
                                         Wih_d2, Whh_d2, bih_d2, bhh_d2, out);
}